// Round 6
// baseline (427.042 us; speedup 1.0000x reference)
//
#include <hip/hip_runtime.h>

#define N_NODES 50000
#define N_EDGES 800000
#define IN_DIM  1200
#define KP      1216               // Wb padded K (cols 1200-1215 zero)
#define OUT_DIM 300
#define BNP     320                // Wb padded rows (300-319 zero)
#define XBS     304                // xb row stride (bf16)
#define NSLOTS  (N_EDGES + N_NODES)
#define NWAVES  ((N_NODES + 31) / 32)          // 1563 waves, 32 rows each
#define GEMM_GRID ((NWAVES + 3) / 4)           // 391 blocks of 4 waves

typedef __attribute__((ext_vector_type(8))) short short8;
typedef __attribute__((ext_vector_type(4))) float f32x4;

__device__ __forceinline__ short f2bf(float f) {
  unsigned u = __builtin_bit_cast(unsigned, f);
  u += 0x7fffu + ((u >> 16) & 1u);            // RNE
  return (short)(u >> 16);
}
__device__ __forceinline__ float bf2f(unsigned short h) {
  return __builtin_bit_cast(float, (unsigned)h << 16);
}
__device__ __forceinline__ float lrelu(float v) { return v > 0.f ? v : 0.2f * v; }

__device__ __forceinline__ float wredMaxF(float v) {
  #pragma unroll
  for (int o = 32; o > 0; o >>= 1) v = fmaxf(v, __shfl_xor(v, o));
  return v;
}
__device__ __forceinline__ float wredSumF(float v) {
  #pragma unroll
  for (int o = 32; o > 0; o >>= 1) v += __shfl_xor(v, o);
  return v;
}

// ---------------- W -> bf16, padded [320][1216]
__global__ __launch_bounds__(256) void wconv(const float* __restrict__ W,
                                             unsigned short* __restrict__ Wb) {
  int f = blockIdx.x * 256 + threadIdx.x;          // one short8 per thread
  if (f >= BNP * KP / 8) return;
  int n = (f * 8) / KP, c = (f * 8) % KP;
  short8 v = {0,0,0,0,0,0,0,0};
  if (n < OUT_DIM && c < IN_DIM) {
    const float4* p = reinterpret_cast<const float4*>(W + (size_t)n * IN_DIM + c);
    float4 f0 = p[0], f1 = p[1];
    v[0]=f2bf(f0.x); v[1]=f2bf(f0.y); v[2]=f2bf(f0.z); v[3]=f2bf(f0.w);
    v[4]=f2bf(f1.x); v[5]=f2bf(f1.y); v[6]=f2bf(f1.z); v[7]=f2bf(f1.w);
  }
  *reinterpret_cast<short8*>(&Wb[(size_t)n * KP + c]) = v;
}

// ---------------- GEMM: xb = z @ W^T, barrier-free, LDS-free.
// One wave = 32 rows (2 M-frags) x 300 cols (19 N-frags), 16x16x32 bf16 MFMA.
// A-frags straight from z (HBM stream, 1-deep ping-pong prefetch);
// B-frags straight from Wb (L2-hot). Fused a_s/a_d epilogue (wave-local).
__global__ __launch_bounds__(256, 2) void gemm_x(const float* __restrict__ z,
                                                 const unsigned short* __restrict__ Wb,
                                                 const float* __restrict__ att_s,
                                                 const float* __restrict__ att_d,
                                                 unsigned short* __restrict__ xb,
                                                 float* __restrict__ a_s,
                                                 float* __restrict__ a_d) {
  const int lane = threadIdx.x & 63;
  const int wid  = threadIdx.x >> 6;
  const int wg   = blockIdx.x * 4 + wid;     // global wave id
  const int m0   = wg * 32;
  if (m0 >= N_NODES) return;

  const int lr = lane & 15;                  // frag row/col
  const int lg = lane >> 4;                  // k-group 0..3

  f32x4 zero4 = {0.f, 0.f, 0.f, 0.f};
  f32x4 acc[2][19];
  #pragma unroll
  for (int mf = 0; mf < 2; ++mf)
    #pragma unroll
    for (int t = 0; t < 19; ++t) acc[mf][t] = zero4;

  const float4 fz4 = make_float4(0.f, 0.f, 0.f, 0.f);
  const int am0 = m0 + lr, am1 = m0 + 16 + lr;
  const bool v0 = am0 < N_NODES, v1 = am1 < N_NODES;
  const float* zp0 = z + (size_t)am0 * IN_DIM + 8 * lg;
  const float* zp1 = z + (size_t)am1 * IN_DIM + 8 * lg;
  const unsigned short* bp = Wb + (size_t)lr * KP + 8 * lg;   // + t*16*KP + ks*32

  // A stage regs: [mf][2 float4]; two named stages (no runtime indexing)
  float4 sA0[2][2], sA1[2][2];

  #define LOADA(ST, KS)                                                        \
    {                                                                          \
      int k = (KS) * 32 + 8 * lg;                                              \
      bool kv = k < IN_DIM;                                                    \
      if (v0 && kv) { const float4* p = reinterpret_cast<const float4*>(zp0 + (KS) * 32); \
        ST[0][0] = p[0]; ST[0][1] = p[1]; } else { ST[0][0] = fz4; ST[0][1] = fz4; } \
      if (v1 && kv) { const float4* p = reinterpret_cast<const float4*>(zp1 + (KS) * 32); \
        ST[1][0] = p[0]; ST[1][1] = p[1]; } else { ST[1][0] = fz4; ST[1][1] = fz4; } \
    }

  #define STEP(ST, KS)                                                         \
    {                                                                          \
      short8 af0, af1;                                                         \
      af0[0]=f2bf(ST[0][0].x); af0[1]=f2bf(ST[0][0].y); af0[2]=f2bf(ST[0][0].z); af0[3]=f2bf(ST[0][0].w); \
      af0[4]=f2bf(ST[0][1].x); af0[5]=f2bf(ST[0][1].y); af0[6]=f2bf(ST[0][1].z); af0[7]=f2bf(ST[0][1].w); \
      af1[0]=f2bf(ST[1][0].x); af1[1]=f2bf(ST[1][0].y); af1[2]=f2bf(ST[1][0].z); af1[3]=f2bf(ST[1][0].w); \
      af1[4]=f2bf(ST[1][1].x); af1[5]=f2bf(ST[1][1].y); af1[6]=f2bf(ST[1][1].z); af1[7]=f2bf(ST[1][1].w); \
      const unsigned short* bk = bp + (KS) * 32;                               \
      {                                                                        \
        short8 b[10];                                                          \
        _Pragma("unroll")                                                      \
        for (int t = 0; t < 10; ++t)                                           \
          b[t] = *reinterpret_cast<const short8*>(bk + (size_t)t * 16 * KP);   \
        _Pragma("unroll")                                                      \
        for (int t = 0; t < 10; ++t) {                                         \
          acc[0][t] = __builtin_amdgcn_mfma_f32_16x16x32_bf16(af0, b[t], acc[0][t], 0, 0, 0); \
          acc[1][t] = __builtin_amdgcn_mfma_f32_16x16x32_bf16(af1, b[t], acc[1][t], 0, 0, 0); \
        }                                                                      \
      }                                                                        \
      {                                                                        \
        short8 b[9];                                                           \
        _Pragma("unroll")                                                      \
        for (int t = 0; t < 9; ++t)                                            \
          b[t] = *reinterpret_cast<const short8*>(bk + (size_t)(t + 10) * 16 * KP); \
        _Pragma("unroll")                                                      \
        for (int t = 0; t < 9; ++t) {                                          \
          acc[0][t+10] = __builtin_amdgcn_mfma_f32_16x16x32_bf16(af0, b[t], acc[0][t+10], 0, 0, 0); \
          acc[1][t+10] = __builtin_amdgcn_mfma_f32_16x16x32_bf16(af1, b[t], acc[1][t+10], 0, 0, 0); \
        }                                                                      \
      }                                                                        \
    }

  LOADA(sA0, 0);
  #pragma unroll 1
  for (int kk = 0; kk < 19; ++kk) {
    const int ks0 = 2 * kk, ks1 = 2 * kk + 1;
    LOADA(sA1, ks1);                 // prefetch odd slice
    STEP(sA0, ks0);
    if (kk < 18) { LOADA(sA0, ks0 + 2); }   // prefetch next even slice
    STEP(sA1, ks1);
  }
  #undef LOADA
  #undef STEP

  // ---- epilogue: bf16 x store + fused logits (wave-local, rows owned by wave)
  float ps[2][4] = {{0,0,0,0},{0,0,0,0}}, pd[2][4] = {{0,0,0,0},{0,0,0,0}};
  #pragma unroll
  for (int t = 0; t < 19; ++t) {
    int c = 16 * t + lr;
    bool cv = c < OUT_DIM;
    float vs = cv ? att_s[c] : 0.f;
    float vd = cv ? att_d[c] : 0.f;
    #pragma unroll
    for (int mf = 0; mf < 2; ++mf) {
      #pragma unroll
      for (int j = 0; j < 4; ++j) {
        float val = acc[mf][t][j];
        int r = m0 + 16 * mf + 4 * lg + j;
        if (cv && r < N_NODES) xb[(size_t)r * XBS + c] = (unsigned short)f2bf(val);
        ps[mf][j] += val * vs;
        pd[mf][j] += val * vd;
      }
    }
  }
  #pragma unroll
  for (int mf = 0; mf < 2; ++mf)
    #pragma unroll
    for (int j = 0; j < 4; ++j) {
      #pragma unroll
      for (int o = 8; o > 0; o >>= 1) {
        ps[mf][j] += __shfl_xor(ps[mf][j], o);
        pd[mf][j] += __shfl_xor(pd[mf][j], o);
      }
      if (lr == 0) {
        int r = m0 + 16 * mf + 4 * lg + j;
        if (r < N_NODES) { a_s[r] = ps[mf][j]; a_d[r] = pd[mf][j]; }
      }
    }
}

// ---------------- CSR build (deg+1 slots per node: +1 self-loop)
__global__ void hist(const int* __restrict__ ei, int* __restrict__ deg) {
  int e = blockIdx.x * blockDim.x + threadIdx.x;
  if (e < N_EDGES) {
    unsigned dst = (unsigned)ei[N_EDGES + e];
    if (dst < N_NODES) atomicAdd(&deg[dst], 1);
  }
}

#define SCAN_B 1024
#define NBLK   49

__global__ __launch_bounds__(SCAN_B) void scan1(const int* __restrict__ deg,
                                                int* __restrict__ bsum) {
  int i = blockIdx.x * SCAN_B + threadIdx.x;
  int v = (i < N_NODES) ? deg[i] + 1 : 0;
  #pragma unroll
  for (int o = 32; o > 0; o >>= 1) v += __shfl_xor(v, o);
  __shared__ int wt[16];
  if ((threadIdx.x & 63) == 0) wt[threadIdx.x >> 6] = v;
  __syncthreads();
  if (threadIdx.x == 0) {
    int t = 0;
    #pragma unroll
    for (int w = 0; w < 16; ++w) t += wt[w];
    bsum[blockIdx.x] = t;
  }
}

__global__ void scan2(const int* __restrict__ bsum, int* __restrict__ bex,
                      int* __restrict__ offs) {
  int l = threadIdx.x;
  int v = (l < NBLK) ? bsum[l] : 0;
  int incl = v;
  #pragma unroll
  for (int off = 1; off < 64; off <<= 1) {
    int u = __shfl_up(incl, off);
    if (l >= off) incl += u;
  }
  if (l < NBLK) bex[l] = incl - v;
  if (l == NBLK - 1) offs[N_NODES] = incl;
}

__global__ __launch_bounds__(SCAN_B) void scan3(const int* __restrict__ deg,
                                                const int* __restrict__ bex,
                                                int* __restrict__ offs,
                                                int* __restrict__ cursor) {
  int tid = threadIdx.x;
  int i = blockIdx.x * SCAN_B + tid;
  int lane = tid & 63, wid = tid >> 6;
  int v = (i < N_NODES) ? deg[i] + 1 : 0;
  int incl = v;
  #pragma unroll
  for (int off = 1; off < 64; off <<= 1) {
    int u = __shfl_up(incl, off);
    if (lane >= off) incl += u;
  }
  __shared__ int wt[16];
  if (lane == 63) wt[wid] = incl;
  __syncthreads();
  if (tid < 16) {
    int t = wt[tid];
    int sc = t;
    #pragma unroll
    for (int off = 1; off < 16; off <<= 1) {
      int u = __shfl_up(sc, off);
      if (tid >= off) sc += u;
    }
    wt[tid] = sc - t;
  }
  __syncthreads();
  int excl = incl - v + wt[wid] + bex[blockIdx.x];
  if (i < N_NODES) { offs[i] = excl; cursor[i] = excl; }
}

__global__ void fill(const int* __restrict__ ei, int* __restrict__ cursor,
                     int* __restrict__ srcs) {
  int e = blockIdx.x * blockDim.x + threadIdx.x;
  if (e < N_EDGES) {
    unsigned dst = (unsigned)ei[N_EDGES + e];
    unsigned src = (unsigned)ei[e];
    if (dst < N_NODES && src < N_NODES) {
      int pos = atomicAdd(&cursor[dst], 1);
      srcs[pos] = (int)src;
    }
  }
}

// ---------------- per-node softmax weights -> packed (src, w), incl self slot
__global__ __launch_bounds__(256) void weights(const float* __restrict__ a_s,
                                               const float* __restrict__ a_d,
                                               const int* __restrict__ offs,
                                               const int* __restrict__ srcs,
                                               int2* __restrict__ packed) {
  int node = blockIdx.x * 4 + (threadIdx.x >> 6);
  if (node >= N_NODES) return;
  int lane = threadIdx.x & 63;
  int beg = offs[node], end = offs[node + 1];
  int ne = end - 1 - beg;                  // true edges (self slot at end-1)
  float adi = a_d[node];
  float eself = lrelu(a_s[node] + adi);

  float m = eself;
  for (int k = lane; k < ne; k += 64)
    m = fmaxf(m, lrelu(a_s[srcs[beg + k]] + adi));
  m = wredMaxF(m);

  float s = 0.f;
  for (int k = lane; k < ne; k += 64)
    s += expf(lrelu(a_s[srcs[beg + k]] + adi) - m);
  s = wredSumF(s) + expf(eself - m);
  float inv = 1.0f / s;

  for (int k = lane; k < ne; k += 64) {
    int sj = srcs[beg + k];
    float w = expf(lrelu(a_s[sj] + adi) - m) * inv;
    packed[beg + k] = make_int2(sj, __float_as_int(w));
  }
  if (lane == 0)
    packed[end - 1] = make_int2(node, __float_as_int(expf(eself - m) * inv));
}

// ---------------- streaming weighted gather: thread = (node, 20-col chunk)
#define CCH 15   // chunks per node
__global__ __launch_bounds__(256) void aggregate(const unsigned short* __restrict__ xb,
                                                 const int2* __restrict__ packed,
                                                 const int* __restrict__ offs,
                                                 const float* __restrict__ bias,
                                                 float* __restrict__ out) {
  unsigned wi = blockIdx.x * 256u + threadIdx.x;
  if (wi >= (unsigned)N_NODES * CCH) return;
  unsigned node = wi / CCH;
  unsigned cc = wi - node * CCH;           // 0..14 -> cols 20cc..20cc+19

  int beg = offs[node], end = offs[node + 1];
  const unsigned short* xcol = xb + 20u * cc;

  float acc[20];
  #pragma unroll
  for (int q = 0; q < 20; ++q) acc[q] = 0.f;

  for (int k = beg; k < end; ++k) {
    int2 pw = packed[k];
    float w = __builtin_bit_cast(float, pw.y);
    const unsigned short* xr = xcol + (size_t)pw.x * XBS;
    #pragma unroll
    for (int q = 0; q < 5; ++q) {
      ushort4 xv = *reinterpret_cast<const ushort4*>(xr + 4 * q);
      acc[4*q+0] += w * bf2f(xv.x);
      acc[4*q+1] += w * bf2f(xv.y);
      acc[4*q+2] += w * bf2f(xv.z);
      acc[4*q+3] += w * bf2f(xv.w);
    }
  }
  float* op = out + (size_t)node * OUT_DIM + 20u * cc;
  const float* bp = bias + 20u * cc;
  #pragma unroll
  for (int q = 0; q < 5; ++q) {
    float4 b = *reinterpret_cast<const float4*>(bp + 4 * q);
    float4 o = {acc[4*q] + b.x, acc[4*q+1] + b.y, acc[4*q+2] + b.z, acc[4*q+3] + b.w};
    *reinterpret_cast<float4*>(op + 4 * q) = o;
  }
}

extern "C" void kernel_launch(void* const* d_in, const int* in_sizes, int n_in,
                              void* d_out, int out_size, void* d_ws, size_t ws_size,
                              hipStream_t stream) {
  const float* z     = (const float*)d_in[0];
  const int*   ei    = (const int*)d_in[1];     // int64 in ref -> int32 on the wire
  const float* W     = (const float*)d_in[2];
  const float* att_s = (const float*)d_in[3];
  const float* att_d = (const float*)d_in[4];
  const float* bias  = (const float*)d_in[5];
  float* out = (float*)d_out;

  char* ws = (char*)d_ws;
  size_t off = 0;
  unsigned short* xb = (unsigned short*)(ws + off); off += (size_t)N_NODES * XBS * 2;  // 30.4 MB
  unsigned short* Wb = (unsigned short*)(ws + off); off += (size_t)BNP * KP * 2;       // 0.78 MB
  float* a_s  = (float*)(ws + off); off += 50048 * 4;
  float* a_d  = (float*)(ws + off); off += 50048 * 4;
  int*   deg  = (int*)(ws + off);   off += 50048 * 4;
  int*   offs = (int*)(ws + off);   off += 50056 * 4;
  int*   cur  = (int*)(ws + off);   off += 50048 * 4;
  int*   bsum = (int*)(ws + off);   off += 64 * 4;
  int*   bex  = (int*)(ws + off);   off += 64 * 4;
  int*   srcs = (int*)(ws + off);   off += (size_t)NSLOTS * 4;
  int2*  pck  = (int2*)(ws + off);  off += (size_t)NSLOTS * 8;

  (void)hipMemsetAsync(deg, 0, N_NODES * 4, stream);

  wconv<<<(BNP * KP / 8 + 255) / 256, 256, 0, stream>>>(W, Wb);
  gemm_x<<<GEMM_GRID, 256, 0, stream>>>(z, Wb, att_s, att_d, xb, a_s, a_d);
  hist<<<(N_EDGES + 255) / 256, 256, 0, stream>>>(ei, deg);
  scan1<<<NBLK, SCAN_B, 0, stream>>>(deg, bsum);
  scan2<<<1, 64, 0, stream>>>(bsum, bex, offs);
  scan3<<<NBLK, SCAN_B, 0, stream>>>(deg, bex, offs, cur);
  fill<<<(N_EDGES + 255) / 256, 256, 0, stream>>>(ei, cur, srcs);
  weights<<<(N_NODES + 3) / 4, 256, 0, stream>>>(a_s, a_d, offs, srcs, pck);
  aggregate<<<((unsigned)N_NODES * CCH + 255) / 256, 256, 0, stream>>>(xb, pck, offs, bias, out);
}

// Round 7
// 397.208 us; speedup vs baseline: 1.0751x; 1.0751x over previous
//
#include <hip/hip_runtime.h>

#define N_NODES 50000
#define N_EDGES 800000
#define IN_DIM  1200
#define KP      1216               // Wb padded K (cols 1200-1215 zero)
#define OUT_DIM 300
#define BNP     320                // Wb padded rows (300-319 zero)
#define XBS     304                // xb row stride (bf16)
#define NSLOTS  (N_EDGES + N_NODES)
#define BM      48
#define GRID_M  ((N_NODES + BM - 1) / BM)   // 1042

typedef __attribute__((ext_vector_type(8))) short short8;
typedef __attribute__((ext_vector_type(4))) short short4v;
typedef __attribute__((ext_vector_type(4))) float f32x4;

__device__ __forceinline__ short f2bf(float f) {
  unsigned u = __builtin_bit_cast(unsigned, f);
  u += 0x7fffu + ((u >> 16) & 1u);            // RNE
  return (short)(u >> 16);
}
__device__ __forceinline__ float bf2f(unsigned short h) {
  return __builtin_bit_cast(float, (unsigned)h << 16);
}
__device__ __forceinline__ float lrelu(float v) { return v > 0.f ? v : 0.2f * v; }

__device__ __forceinline__ float wredMaxF(float v) {
  #pragma unroll
  for (int o = 32; o > 0; o >>= 1) v = fmaxf(v, __shfl_xor(v, o));
  return v;
}
__device__ __forceinline__ float wredSumF(float v) {
  #pragma unroll
  for (int o = 32; o > 0; o >>= 1) v += __shfl_xor(v, o);
  return v;
}

// ---------------- W -> bf16, padded [320][1216]
__global__ __launch_bounds__(256) void wconv(const float* __restrict__ W,
                                             unsigned short* __restrict__ Wb) {
  int f = blockIdx.x * 256 + threadIdx.x;          // one short8 per thread
  if (f >= BNP * KP / 8) return;
  int n = (f * 8) / KP, c = (f * 8) % KP;
  short8 v = {0,0,0,0,0,0,0,0};
  if (n < OUT_DIM && c < IN_DIM) {
    const float4* p = reinterpret_cast<const float4*>(W + (size_t)n * IN_DIM + c);
    float4 f0 = p[0], f1 = p[1];
    v[0]=f2bf(f0.x); v[1]=f2bf(f0.y); v[2]=f2bf(f0.z); v[3]=f2bf(f0.w);
    v[4]=f2bf(f1.x); v[5]=f2bf(f1.y); v[6]=f2bf(f1.z); v[7]=f2bf(f1.w);
  }
  *reinterpret_cast<short8*>(&Wb[(size_t)n * KP + c]) = v;
}

// ---------------- GEMM: xb = z @ W^T (bf16 MFMA), fused a_s/a_d epilogue.
// BM=48, BK=64, 4 waves N-split (wave w = cols 80w..80w+79, 5 N-frags x 3 M-frags).
// A: LDS bf16, double-buffered, XOR-swizzled; staged via regs one K-tile ahead.
// B: direct from Wb (L2-resident; 12 waves/CU of TLP hide latency).
__global__ __launch_bounds__(256, 3) void gemm_x(const float* __restrict__ z,
                                                 const unsigned short* __restrict__ Wb,
                                                 const float* __restrict__ att_s,
                                                 const float* __restrict__ att_d,
                                                 unsigned short* __restrict__ xb,
                                                 float* __restrict__ a_s,
                                                 float* __restrict__ a_d) {
  __shared__ unsigned short As[2][BM * 64];   // 2 x 6 KB, chunk-XOR swizzled

  const int tid  = threadIdx.x;
  const int lane = tid & 63;
  const int wid  = tid >> 6;
  const int lr   = lane & 15;
  const int lg   = lane >> 4;
  const int m0   = blockIdx.x * BM;

  f32x4 zero4 = {0.f, 0.f, 0.f, 0.f};
  const float4 fz4 = make_float4(0.f, 0.f, 0.f, 0.f);
  f32x4 acc[3][5];
  #pragma unroll
  for (int mf = 0; mf < 3; ++mf)
    #pragma unroll
    for (int nj = 0; nj < 5; ++nj) acc[mf][nj] = zero4;

  // B pointer: row = 80*wid + 16*nj + lr (< 320, padded), k = kt*64 + ks*32 + 8lg
  const unsigned short* bp = Wb + (size_t)(80 * wid + lr) * KP + 8 * lg;

  // A staging: float4 index fi = tid + 256q (q<3); row = fi>>4, f4c = fi&15
  const int srow_[3] = { (tid      ) >> 4, (tid + 256) >> 4, (tid + 512) >> 4 };
  const int sf4c_[3] = { (tid      ) & 15, (tid + 256) & 15, (tid + 512) & 15 };
  float4 sg[3];

  #define LOADST(KT)                                                           \
    _Pragma("unroll")                                                          \
    for (int q = 0; q < 3; ++q) {                                              \
      int m = m0 + srow_[q];                                                   \
      int k = (KT) * 64 + sf4c_[q] * 4;                                        \
      sg[q] = (m < N_NODES && k < IN_DIM)                                      \
        ? *reinterpret_cast<const float4*>(z + (size_t)m * IN_DIM + k)         \
        : fz4;                                                                 \
    }

  #define WRITEST(BUF)                                                         \
    _Pragma("unroll")                                                          \
    for (int q = 0; q < 3; ++q) {                                              \
      short4v v;                                                               \
      v[0]=f2bf(sg[q].x); v[1]=f2bf(sg[q].y); v[2]=f2bf(sg[q].z); v[3]=f2bf(sg[q].w); \
      int row = srow_[q], f4c = sf4c_[q];                                      \
      int c2 = (f4c >> 1) ^ (row & 7);                                         \
      *reinterpret_cast<short4v*>(&As[BUF][row * 64 + c2 * 8 + (f4c & 1) * 4]) = v; \
    }

  LOADST(0);
  WRITEST(0);
  __syncthreads();

  #pragma unroll 1
  for (int kt = 0; kt < 19; ++kt) {
    const int cur = kt & 1;
    if (kt < 18) { LOADST(kt + 1); }       // issue next A tile (HBM) early

    const unsigned short* bpk = bp + kt * 64;
    #pragma unroll
    for (int ks = 0; ks < 2; ++ks) {
      const unsigned short* bk = bpk + ks * 32;
      short8 b0 = *reinterpret_cast<const short8*>(bk);
      short8 b1 = *reinterpret_cast<const short8*>(bk + (size_t)16 * KP);
      short8 b2 = *reinterpret_cast<const short8*>(bk + (size_t)32 * KP);
      short8 b3 = *reinterpret_cast<const short8*>(bk + (size_t)48 * KP);
      short8 b4 = *reinterpret_cast<const short8*>(bk + (size_t)64 * KP);
      const int ch = ks * 4 + lg;
      short8 a0, a1, a2;
      {
        int r0 = lr,      c0 = (ch ^ (r0 & 7));
        int r1 = 16 + lr, c1 = (ch ^ (r1 & 7));
        int r2 = 32 + lr, c2 = (ch ^ (r2 & 7));
        a0 = *reinterpret_cast<const short8*>(&As[cur][r0 * 64 + c0 * 8]);
        a1 = *reinterpret_cast<const short8*>(&As[cur][r1 * 64 + c1 * 8]);
        a2 = *reinterpret_cast<const short8*>(&As[cur][r2 * 64 + c2 * 8]);
      }
      acc[0][0] = __builtin_amdgcn_mfma_f32_16x16x32_bf16(a0, b0, acc[0][0], 0, 0, 0);
      acc[1][0] = __builtin_amdgcn_mfma_f32_16x16x32_bf16(a1, b0, acc[1][0], 0, 0, 0);
      acc[2][0] = __builtin_amdgcn_mfma_f32_16x16x32_bf16(a2, b0, acc[2][0], 0, 0, 0);
      acc[0][1] = __builtin_amdgcn_mfma_f32_16x16x32_bf16(a0, b1, acc[0][1], 0, 0, 0);
      acc[1][1] = __builtin_amdgcn_mfma_f32_16x16x32_bf16(a1, b1, acc[1][1], 0, 0, 0);
      acc[2][1] = __builtin_amdgcn_mfma_f32_16x16x32_bf16(a2, b1, acc[2][1], 0, 0, 0);
      acc[0][2] = __builtin_amdgcn_mfma_f32_16x16x32_bf16(a0, b2, acc[0][2], 0, 0, 0);
      acc[1][2] = __builtin_amdgcn_mfma_f32_16x16x32_bf16(a1, b2, acc[1][2], 0, 0, 0);
      acc[2][2] = __builtin_amdgcn_mfma_f32_16x16x32_bf16(a2, b2, acc[2][2], 0, 0, 0);
      acc[0][3] = __builtin_amdgcn_mfma_f32_16x16x32_bf16(a0, b3, acc[0][3], 0, 0, 0);
      acc[1][3] = __builtin_amdgcn_mfma_f32_16x16x32_bf16(a1, b3, acc[1][3], 0, 0, 0);
      acc[2][3] = __builtin_amdgcn_mfma_f32_16x16x32_bf16(a2, b3, acc[2][3], 0, 0, 0);
      acc[0][4] = __builtin_amdgcn_mfma_f32_16x16x32_bf16(a0, b4, acc[0][4], 0, 0, 0);
      acc[1][4] = __builtin_amdgcn_mfma_f32_16x16x32_bf16(a1, b4, acc[1][4], 0, 0, 0);
      acc[2][4] = __builtin_amdgcn_mfma_f32_16x16x32_bf16(a2, b4, acc[2][4], 0, 0, 0);
    }

    if (kt < 18) {
      WRITEST(cur ^ 1);                    // waits on LOADST, fills other buffer
      __syncthreads();
    }
  }
  #undef LOADST
  #undef WRITEST

  // ---- epilogue: bf16 x store + fused logits (cross-wave LDS reduce)
  __syncthreads();
  float* red = reinterpret_cast<float*>(&As[0][0]);  // [2][4][48] floats

  float vs[5], vd[5];
  #pragma unroll
  for (int nj = 0; nj < 5; ++nj) {
    int c = 80 * wid + 16 * nj + lr;
    bool cv = c < OUT_DIM;
    vs[nj] = cv ? att_s[c] : 0.f;
    vd[nj] = cv ? att_d[c] : 0.f;
  }

  #pragma unroll
  for (int mf = 0; mf < 3; ++mf) {
    float ps[4] = {0.f,0.f,0.f,0.f}, pd[4] = {0.f,0.f,0.f,0.f};
    #pragma unroll
    for (int nj = 0; nj < 5; ++nj) {
      int c = 80 * wid + 16 * nj + lr;
      bool cv = c < OUT_DIM;
      #pragma unroll
      for (int jj = 0; jj < 4; ++jj) {
        float val = acc[mf][nj][jj];
        int r = m0 + 16 * mf + 4 * lg + jj;
        if (cv && r < N_NODES) xb[(size_t)r * XBS + c] = (unsigned short)f2bf(val);
        ps[jj] += val * vs[nj];
        pd[jj] += val * vd[nj];
      }
    }
    #pragma unroll
    for (int jj = 0; jj < 4; ++jj) {
      #pragma unroll
      for (int o = 8; o > 0; o >>= 1) {
        ps[jj] += __shfl_xor(ps[jj], o);
        pd[jj] += __shfl_xor(pd[jj], o);
      }
    }
    if (lr == 0) {
      #pragma unroll
      for (int jj = 0; jj < 4; ++jj) {
        int rr = 16 * mf + 4 * lg + jj;
        red[wid * 48 + rr]       = ps[jj];
        red[192 + wid * 48 + rr] = pd[jj];
      }
    }
  }
  __syncthreads();
  if (tid < 48) {
    int r = m0 + tid;
    if (r < N_NODES)
      a_s[r] = red[tid] + red[48 + tid] + red[96 + tid] + red[144 + tid];
  } else if (tid < 96) {
    int t = tid - 48, r = m0 + t;
    if (r < N_NODES)
      a_d[r] = red[192 + t] + red[192 + 48 + t] + red[192 + 96 + t] + red[192 + 144 + t];
  }
}

// ---------------- CSR build (deg+1 slots per node: +1 self-loop)
__global__ void hist(const int* __restrict__ ei, int* __restrict__ deg) {
  int e = blockIdx.x * blockDim.x + threadIdx.x;
  if (e < N_EDGES) {
    unsigned dst = (unsigned)ei[N_EDGES + e];
    if (dst < N_NODES) atomicAdd(&deg[dst], 1);
  }
}

#define SCAN_B 1024
#define NBLK   49

__global__ __launch_bounds__(SCAN_B) void scan1(const int* __restrict__ deg,
                                                int* __restrict__ bsum) {
  int i = blockIdx.x * SCAN_B + threadIdx.x;
  int v = (i < N_NODES) ? deg[i] + 1 : 0;
  #pragma unroll
  for (int o = 32; o > 0; o >>= 1) v += __shfl_xor(v, o);
  __shared__ int wt[16];
  if ((threadIdx.x & 63) == 0) wt[threadIdx.x >> 6] = v;
  __syncthreads();
  if (threadIdx.x == 0) {
    int t = 0;
    #pragma unroll
    for (int w = 0; w < 16; ++w) t += wt[w];
    bsum[blockIdx.x] = t;
  }
}

__global__ void scan2(const int* __restrict__ bsum, int* __restrict__ bex,
                      int* __restrict__ offs) {
  int l = threadIdx.x;
  int v = (l < NBLK) ? bsum[l] : 0;
  int incl = v;
  #pragma unroll
  for (int off = 1; off < 64; off <<= 1) {
    int u = __shfl_up(incl, off);
    if (l >= off) incl += u;
  }
  if (l < NBLK) bex[l] = incl - v;
  if (l == NBLK - 1) offs[N_NODES] = incl;
}

__global__ __launch_bounds__(SCAN_B) void scan3(const int* __restrict__ deg,
                                                const int* __restrict__ bex,
                                                int* __restrict__ offs,
                                                int* __restrict__ cursor) {
  int tid = threadIdx.x;
  int i = blockIdx.x * SCAN_B + tid;
  int lane = tid & 63, wid = tid >> 6;
  int v = (i < N_NODES) ? deg[i] + 1 : 0;
  int incl = v;
  #pragma unroll
  for (int off = 1; off < 64; off <<= 1) {
    int u = __shfl_up(incl, off);
    if (lane >= off) incl += u;
  }
  __shared__ int wt[16];
  if (lane == 63) wt[wid] = incl;
  __syncthreads();
  if (tid < 16) {
    int t = wt[tid];
    int sc = t;
    #pragma unroll
    for (int off = 1; off < 16; off <<= 1) {
      int u = __shfl_up(sc, off);
      if (tid >= off) sc += u;
    }
    wt[tid] = sc - t;
  }
  __syncthreads();
  int excl = incl - v + wt[wid] + bex[blockIdx.x];
  if (i < N_NODES) { offs[i] = excl; cursor[i] = excl; }
}

__global__ void fill(const int* __restrict__ ei, int* __restrict__ cursor,
                     int* __restrict__ srcs) {
  int e = blockIdx.x * blockDim.x + threadIdx.x;
  if (e < N_EDGES) {
    unsigned dst = (unsigned)ei[N_EDGES + e];
    unsigned src = (unsigned)ei[e];
    if (dst < N_NODES && src < N_NODES) {
      int pos = atomicAdd(&cursor[dst], 1);
      srcs[pos] = (int)src;
    }
  }
}

// ---------------- per-node softmax weights -> packed (src, w), incl self slot
__global__ __launch_bounds__(256) void weights(const float* __restrict__ a_s,
                                               const float* __restrict__ a_d,
                                               const int* __restrict__ offs,
                                               const int* __restrict__ srcs,
                                               int2* __restrict__ packed) {
  int node = blockIdx.x * 4 + (threadIdx.x >> 6);
  if (node >= N_NODES) return;
  int lane = threadIdx.x & 63;
  int beg = offs[node], end = offs[node + 1];
  int ne = end - 1 - beg;                  // true edges (self slot at end-1)
  float adi = a_d[node];
  float eself = lrelu(a_s[node] + adi);

  float m = eself;
  for (int k = lane; k < ne; k += 64)
    m = fmaxf(m, lrelu(a_s[srcs[beg + k]] + adi));
  m = wredMaxF(m);

  float s = 0.f;
  for (int k = lane; k < ne; k += 64)
    s += expf(lrelu(a_s[srcs[beg + k]] + adi) - m);
  s = wredSumF(s) + expf(eself - m);
  float inv = 1.0f / s;

  for (int k = lane; k < ne; k += 64) {
    int sj = srcs[beg + k];
    float w = expf(lrelu(a_s[sj] + adi) - m) * inv;
    packed[beg + k] = make_int2(sj, __float_as_int(w));
  }
  if (lane == 0)
    packed[end - 1] = make_int2(node, __float_as_int(expf(eself - m) * inv));
}

// ---------------- streaming weighted gather: thread = (node, 20-col chunk)
#define CCH 15   // chunks per node
__global__ __launch_bounds__(256) void aggregate(const unsigned short* __restrict__ xb,
                                                 const int2* __restrict__ packed,
                                                 const int* __restrict__ offs,
                                                 const float* __restrict__ bias,
                                                 float* __restrict__ out) {
  unsigned wi = blockIdx.x * 256u + threadIdx.x;
  if (wi >= (unsigned)N_NODES * CCH) return;
  unsigned node = wi / CCH;
  unsigned cc = wi - node * CCH;           // 0..14 -> cols 20cc..20cc+19

  int beg = offs[node], end = offs[node + 1];
  const unsigned short* xcol = xb + 20u * cc;

  float acc[20];
  #pragma unroll
  for (int q = 0; q < 20; ++q) acc[q] = 0.f;

  for (int k = beg; k < end; ++k) {
    int2 pw = packed[k];
    float w = __builtin_bit_cast(float, pw.y);
    const unsigned short* xr = xcol + (size_t)pw.x * XBS;
    #pragma unroll
    for (int q = 0; q < 5; ++q) {
      ushort4 xv = *reinterpret_cast<const ushort4*>(xr + 4 * q);
      acc[4*q+0] += w * bf2f(xv.x);
      acc[4*q+1] += w * bf2f(xv.y);
      acc[4*q+2] += w * bf2f(xv.z);
      acc[4*q+3] += w * bf2f(xv.w);
    }
  }
  float* op = out + (size_t)node * OUT_DIM + 20u * cc;
  const float* bp = bias + 20u * cc;
  #pragma unroll
  for (int q = 0; q < 5; ++q) {
    float4 b = *reinterpret_cast<const float4*>(bp + 4 * q);
    float4 o = {acc[4*q] + b.x, acc[4*q+1] + b.y, acc[4*q+2] + b.z, acc[4*q+3] + b.w};
    *reinterpret_cast<float4*>(op + 4 * q) = o;
  }
}

extern "C" void kernel_launch(void* const* d_in, const int* in_sizes, int n_in,
                              void* d_out, int out_size, void* d_ws, size_t ws_size,
                              hipStream_t stream) {
  const float* z     = (const float*)d_in[0];
  const int*   ei    = (const int*)d_in[1];     // int64 in ref -> int32 on the wire
  const float* W     = (const float*)d_in[2];
  const float* att_s = (const float*)d_in[3];
  const float* att_d = (const float*)d_in[4];
  const float* bias  = (const float*)d_in[5];
  float* out = (float*)d_out;

  char* ws = (char*)d_ws;
  size_t off = 0;
  unsigned short* xb = (unsigned short*)(ws + off); off += (size_t)N_NODES * XBS * 2;  // 30.4 MB
  unsigned short* Wb = (unsigned short*)(ws + off); off += (size_t)BNP * KP * 2;       // 0.78 MB
  float* a_s  = (float*)(ws + off); off += 50048 * 4;
  float* a_d  = (float*)(ws + off); off += 50048 * 4;
  int*   deg  = (int*)(ws + off);   off += 50048 * 4;
  int*   offs = (int*)(ws + off);   off += 50056 * 4;
  int*   cur  = (int*)(ws + off);   off += 50048 * 4;
  int*   bsum = (int*)(ws + off);   off += 64 * 4;
  int*   bex  = (int*)(ws + off);   off += 64 * 4;
  int*   srcs = (int*)(ws + off);   off += (size_t)NSLOTS * 4;
  int2*  pck  = (int2*)(ws + off);  off += (size_t)NSLOTS * 8;

  (void)hipMemsetAsync(deg, 0, N_NODES * 4, stream);

  wconv<<<(BNP * KP / 8 + 255) / 256, 256, 0, stream>>>(W, Wb);
  gemm_x<<<GRID_M, 256, 0, stream>>>(z, Wb, att_s, att_d, xb, a_s, a_d);
  hist<<<(N_EDGES + 255) / 256, 256, 0, stream>>>(ei, deg);
  scan1<<<NBLK, SCAN_B, 0, stream>>>(deg, bsum);
  scan2<<<1, 64, 0, stream>>>(bsum, bex, offs);
  scan3<<<NBLK, SCAN_B, 0, stream>>>(deg, bex, offs, cur);
  fill<<<(N_EDGES + 255) / 256, 256, 0, stream>>>(ei, cur, srcs);
  weights<<<(N_NODES + 3) / 4, 256, 0, stream>>>(a_s, a_d, offs, srcs, pck);
  aggregate<<<((unsigned)N_NODES * CCH + 255) / 256, 256, 0, stream>>>(xb, pck, offs, bias, out);
}

// Round 8
// 333.055 us; speedup vs baseline: 1.2822x; 1.1926x over previous
//
#include <hip/hip_runtime.h>

#define N_NODES 50000
#define N_EDGES 800000
#define IN_DIM  1200
#define KP      1216               // Wb padded K
#define OUT_DIM 300
#define BNP     320                // Wb padded rows
#define XBS     304                // xb row stride (bf16)
#define BM      64
#define NKT     38                 // K-steps of 32
#define GRID_M  ((N_NODES + BM - 1) / BM)   // 782

typedef __attribute__((ext_vector_type(8))) short short8;
typedef __attribute__((ext_vector_type(4))) float f32x4;

__device__ __forceinline__ short f2bf(float f) {
  unsigned u = __builtin_bit_cast(unsigned, f);
  u += 0x7fffu + ((u >> 16) & 1u);            // RNE
  return (short)(u >> 16);
}
__device__ __forceinline__ float bf2f(unsigned short h) {
  return __builtin_bit_cast(float, (unsigned)h << 16);
}
__device__ __forceinline__ float lrelu(float v) { return v > 0.f ? v : 0.2f * v; }

__device__ __forceinline__ float wredMaxF(float v) {
  #pragma unroll
  for (int o = 32; o > 0; o >>= 1) v = fmaxf(v, __shfl_xor(v, o));
  return v;
}
__device__ __forceinline__ float wredSumF(float v) {
  #pragma unroll
  for (int o = 32; o > 0; o >>= 1) v += __shfl_xor(v, o);
  return v;
}

// ---------------- W -> bf16, padded [320][1216]
__global__ __launch_bounds__(256) void wconv(const float* __restrict__ W,
                                             unsigned short* __restrict__ Wb) {
  int f = blockIdx.x * 256 + threadIdx.x;
  if (f >= BNP * KP / 8) return;
  int n = (f * 8) / KP, c = (f * 8) % KP;
  short8 v = {0,0,0,0,0,0,0,0};
  if (n < OUT_DIM && c < IN_DIM) {
    const float4* p = reinterpret_cast<const float4*>(W + (size_t)n * IN_DIM + c);
    float4 f0 = p[0], f1 = p[1];
    v[0]=f2bf(f0.x); v[1]=f2bf(f0.y); v[2]=f2bf(f0.z); v[3]=f2bf(f0.w);
    v[4]=f2bf(f1.x); v[5]=f2bf(f1.y); v[6]=f2bf(f1.z); v[7]=f2bf(f1.w);
  }
  *reinterpret_cast<short8*>(&Wb[(size_t)n * KP + c]) = v;
}

// ---------------- GEMM: xb = z @ W^T. BM=64, BN=320, BK=32.
// 4 waves = 2Mw x 2Nw; wave = 2 M-frags x 10 N-frags (20 MFMA, 12 ds_read/step).
// A(f32->bf16) + B(bf16 copy) both LDS, XOR-swizzled, double-buffered,
// single barrier/step; next-step global loads issued BEFORE compute (T14).
__global__ __launch_bounds__(256) void gemm_x(const float* __restrict__ z,
                                              const unsigned short* __restrict__ Wb,
                                              const float* __restrict__ att_s,
                                              const float* __restrict__ att_d,
                                              unsigned short* __restrict__ xb,
                                              float* __restrict__ a_s,
                                              float* __restrict__ a_d) {
  __shared__ __align__(16) unsigned short As[2][BM * 32];    // 2 x 4 KB
  __shared__ __align__(16) unsigned short Bs[2][BNP * 32];   // 2 x 20 KB

  const int tid  = threadIdx.x;
  const int lane = tid & 63;
  const int wid  = tid >> 6;
  const int lr   = lane & 15;
  const int lg   = lane >> 4;
  const int mw   = wid >> 1;           // 0..1
  const int nw   = wid & 1;            // 0..1
  const int m0   = blockIdx.x * BM;

  f32x4 zero4 = {0.f, 0.f, 0.f, 0.f};
  const float4 fz4 = make_float4(0.f, 0.f, 0.f, 0.f);
  f32x4 acc[2][10];
  #pragma unroll
  for (int mf = 0; mf < 2; ++mf)
    #pragma unroll
    for (int nj = 0; nj < 10; ++nj) acc[mf][nj] = zero4;

  // A stage: thread t -> row ra=t>>2 (0..63), chunk ca=t&3 (8 k each)
  const int ra = tid >> 2, ca = tid & 3;
  const int am = m0 + ra;
  // B stage: slots s=t+256j -> row rb=s>>2 (0..319), chunk cb=s&3
  float4 ga0, ga1;
  short8 gb[5];

  #define LOADAB(KT)                                                          \
    {                                                                         \
      int k = (KT) * 32 + ca * 8;                                             \
      if (am < N_NODES && k < IN_DIM) {                                       \
        const float4* p = reinterpret_cast<const float4*>(z + (size_t)am * IN_DIM + k); \
        ga0 = p[0]; ga1 = p[1];                                               \
      } else { ga0 = fz4; ga1 = fz4; }                                        \
      _Pragma("unroll")                                                       \
      for (int j = 0; j < 5; ++j) {                                           \
        int s = tid + 256 * j;                                                \
        gb[j] = *reinterpret_cast<const short8*>(                             \
            Wb + (size_t)(s >> 2) * KP + (KT) * 32 + (s & 3) * 8);            \
      }                                                                       \
    }

  #define WRITEST(BUF)                                                        \
    {                                                                         \
      short8 v;                                                               \
      v[0]=f2bf(ga0.x); v[1]=f2bf(ga0.y); v[2]=f2bf(ga0.z); v[3]=f2bf(ga0.w); \
      v[4]=f2bf(ga1.x); v[5]=f2bf(ga1.y); v[6]=f2bf(ga1.z); v[7]=f2bf(ga1.w); \
      int c2a = ca ^ ((ra >> 2) & 3);                                         \
      *reinterpret_cast<short8*>(&As[BUF][ra * 32 + c2a * 8]) = v;            \
      _Pragma("unroll")                                                       \
      for (int j = 0; j < 5; ++j) {                                           \
        int s = tid + 256 * j;                                                \
        int rb = s >> 2, cb = s & 3;                                          \
        int c2b = cb ^ ((rb >> 2) & 3);                                       \
        *reinterpret_cast<short8*>(&Bs[BUF][rb * 32 + c2b * 8]) = gb[j];      \
      }                                                                       \
    }

  LOADAB(0);
  WRITEST(0);
  __syncthreads();

  #pragma unroll 1
  for (int kt = 0; kt < NKT; ++kt) {
    const int cur = kt & 1;
    if (kt < NKT - 1) { LOADAB(kt + 1); }   // issue-early: in flight across compute

    // A frags (2 M): row = mw*32 + mf*16 + lr
    short8 a0, a1;
    {
      int r0 = mw * 32 + lr,      ch0 = lg ^ ((r0 >> 2) & 3);
      int r1 = mw * 32 + 16 + lr, ch1 = lg ^ ((r1 >> 2) & 3);
      a0 = *reinterpret_cast<const short8*>(&As[cur][r0 * 32 + ch0 * 8]);
      a1 = *reinterpret_cast<const short8*>(&As[cur][r1 * 32 + ch1 * 8]);
    }
    // B frags (10 N): row = nw*160 + nj*16 + lr
    #pragma unroll
    for (int nj = 0; nj < 10; ++nj) {
      int rb = nw * 160 + nj * 16 + lr;
      int ch = lg ^ ((rb >> 2) & 3);
      short8 b = *reinterpret_cast<const short8*>(&Bs[cur][rb * 32 + ch * 8]);
      acc[0][nj] = __builtin_amdgcn_mfma_f32_16x16x32_bf16(a0, b, acc[0][nj], 0, 0, 0);
      acc[1][nj] = __builtin_amdgcn_mfma_f32_16x16x32_bf16(a1, b, acc[1][nj], 0, 0, 0);
    }

    if (kt < NKT - 1) {
      WRITEST(cur ^ 1);          // write-late: vmcnt waits land here
      __syncthreads();
    }
  }
  #undef LOADAB
  #undef WRITEST

  // ---- epilogue: bf16 x store + fused logits, cross-nw LDS reduce
  float* red = reinterpret_cast<float*>(&As[0][0]);  // [2 sd][2 nw][64 rows] = 1 KB

  float ps[2][4] = {{0,0,0,0},{0,0,0,0}}, pd[2][4] = {{0,0,0,0},{0,0,0,0}};
  #pragma unroll
  for (int nj = 0; nj < 10; ++nj) {
    int c = nw * 160 + nj * 16 + lr;
    bool cv = c < OUT_DIM;
    float vs = cv ? att_s[c] : 0.f;
    float vd = cv ? att_d[c] : 0.f;
    #pragma unroll
    for (int mf = 0; mf < 2; ++mf) {
      #pragma unroll
      for (int jj = 0; jj < 4; ++jj) {
        float val = acc[mf][nj][jj];
        int r = m0 + mw * 32 + mf * 16 + 4 * lg + jj;
        if (cv && r < N_NODES) xb[(size_t)r * XBS + c] = (unsigned short)f2bf(val);
        ps[mf][jj] += val * vs;
        pd[mf][jj] += val * vd;
      }
    }
  }
  #pragma unroll
  for (int mf = 0; mf < 2; ++mf)
    #pragma unroll
    for (int jj = 0; jj < 4; ++jj) {
      #pragma unroll
      for (int o = 8; o > 0; o >>= 1) {
        ps[mf][jj] += __shfl_xor(ps[mf][jj], o);
        pd[mf][jj] += __shfl_xor(pd[mf][jj], o);
      }
      if (lr == 0) {
        int rr = mw * 32 + mf * 16 + 4 * lg + jj;
        red[nw * 64 + rr]       = ps[mf][jj];
        red[128 + nw * 64 + rr] = pd[mf][jj];
      }
    }
  __syncthreads();
  if (tid < 64) {
    int r = m0 + tid;
    if (r < N_NODES) a_s[r] = red[tid] + red[64 + tid];
  } else if (tid < 128) {
    int t = tid - 64, r = m0 + t;
    if (r < N_NODES) a_d[r] = red[128 + t] + red[192 + t];
  }
}

// ---------------- CSR build (edges only; self-loops handled analytically)
__global__ void hist(const int* __restrict__ ei, int* __restrict__ deg) {
  int e = blockIdx.x * blockDim.x + threadIdx.x;
  if (e < N_EDGES) {
    unsigned dst = (unsigned)ei[N_EDGES + e];
    if (dst < N_NODES) atomicAdd(&deg[dst], 1);
  }
}

#define SCAN_B 1024
#define NBLK   49

__global__ __launch_bounds__(SCAN_B) void scan1(const int* __restrict__ deg,
                                                int* __restrict__ bsum) {
  int i = blockIdx.x * SCAN_B + threadIdx.x;
  int v = (i < N_NODES) ? deg[i] : 0;
  #pragma unroll
  for (int o = 32; o > 0; o >>= 1) v += __shfl_xor(v, o);
  __shared__ int wt[16];
  if ((threadIdx.x & 63) == 0) wt[threadIdx.x >> 6] = v;
  __syncthreads();
  if (threadIdx.x == 0) {
    int t = 0;
    #pragma unroll
    for (int w = 0; w < 16; ++w) t += wt[w];
    bsum[blockIdx.x] = t;
  }
}

__global__ void scan2(const int* __restrict__ bsum, int* __restrict__ bex,
                      int* __restrict__ offs) {
  int l = threadIdx.x;
  int v = (l < NBLK) ? bsum[l] : 0;
  int incl = v;
  #pragma unroll
  for (int off = 1; off < 64; off <<= 1) {
    int u = __shfl_up(incl, off);
    if (l >= off) incl += u;
  }
  if (l < NBLK) bex[l] = incl - v;
  if (l == NBLK - 1) offs[N_NODES] = incl;
}

__global__ __launch_bounds__(SCAN_B) void scan3(const int* __restrict__ deg,
                                                const int* __restrict__ bex,
                                                int* __restrict__ offs,
                                                int* __restrict__ cursor) {
  int tid = threadIdx.x;
  int i = blockIdx.x * SCAN_B + tid;
  int lane = tid & 63, wid = tid >> 6;
  int v = (i < N_NODES) ? deg[i] : 0;
  int incl = v;
  #pragma unroll
  for (int off = 1; off < 64; off <<= 1) {
    int u = __shfl_up(incl, off);
    if (lane >= off) incl += u;
  }
  __shared__ int wt[16];
  if (lane == 63) wt[wid] = incl;
  __syncthreads();
  if (tid < 16) {
    int t = wt[tid];
    int sc = t;
    #pragma unroll
    for (int off = 1; off < 16; off <<= 1) {
      int u = __shfl_up(sc, off);
      if (tid >= off) sc += u;
    }
    wt[tid] = sc - t;
  }
  __syncthreads();
  int excl = incl - v + wt[wid] + bex[blockIdx.x];
  if (i < N_NODES) { offs[i] = excl; cursor[i] = excl; }
}

__global__ void fill(const int* __restrict__ ei, int* __restrict__ cursor,
                     int* __restrict__ srcs) {
  int e = blockIdx.x * blockDim.x + threadIdx.x;
  if (e < N_EDGES) {
    unsigned dst = (unsigned)ei[N_EDGES + e];
    unsigned src = (unsigned)ei[e];
    if (dst < N_NODES && src < N_NODES) {
      int pos = atomicAdd(&cursor[dst], 1);
      srcs[pos] = (int)src;
    }
  }
}

// ---------------- per-node softmax stats (m, 1/s) — wave per node
__global__ __launch_bounds__(256) void minv_k(const float* __restrict__ a_s,
                                              const float* __restrict__ a_d,
                                              const int* __restrict__ offs,
                                              const int* __restrict__ srcs,
                                              float2* __restrict__ minv) {
  int node = blockIdx.x * 4 + (threadIdx.x >> 6);
  if (node >= N_NODES) return;
  int lane = threadIdx.x & 63;
  int beg = offs[node], end = offs[node + 1];
  float adi = a_d[node];
  float eself = lrelu(a_s[node] + adi);

  float m = eself;
  for (int k = beg + lane; k < end; k += 64)
    m = fmaxf(m, lrelu(a_s[srcs[k]] + adi));
  m = wredMaxF(m);

  float s = 0.f;
  for (int k = beg + lane; k < end; k += 64)
    s += expf(lrelu(a_s[srcs[k]] + adi) - m);
  s = wredSumF(s) + expf(eself - m);
  if (lane == 0) minv[node] = make_float2(m, 1.0f / s);
}

// ---------------- streaming weighted gather: thread = (node, 20-col chunk)
// w recomputed inline: 15 chunk-lanes of a node share srcs/a_s addresses
// (broadcast loads) and the redundant exp is SIMD-free.
#define CCH 15
__global__ __launch_bounds__(256) void aggregate(const unsigned short* __restrict__ xb,
                                                 const float* __restrict__ a_s,
                                                 const float* __restrict__ a_d,
                                                 const float2* __restrict__ minv,
                                                 const int* __restrict__ offs,
                                                 const int* __restrict__ srcs,
                                                 const float* __restrict__ bias,
                                                 float* __restrict__ out) {
  unsigned wi = blockIdx.x * 256u + threadIdx.x;
  if (wi >= (unsigned)N_NODES * CCH) return;
  unsigned node = wi / CCH;
  unsigned cc = wi - node * CCH;           // cols 20cc..20cc+19

  int beg = offs[node], end = offs[node + 1];
  float2 mi = minv[node];
  const float m = mi.x, inv = mi.y;
  const float adi = a_d[node];
  const float wself = expf(lrelu(a_s[node] + adi) - m) * inv;

  const unsigned short* xcol = xb + 20u * cc;

  float acc[20];
  {
    const unsigned short* xr = xcol + (size_t)node * XBS;
    #pragma unroll
    for (int q = 0; q < 5; ++q) {
      ushort4 xv = *reinterpret_cast<const ushort4*>(xr + 4 * q);
      acc[4*q+0] = wself * bf2f(xv.x);
      acc[4*q+1] = wself * bf2f(xv.y);
      acc[4*q+2] = wself * bf2f(xv.z);
      acc[4*q+3] = wself * bf2f(xv.w);
    }
  }

  for (int k = beg; k < end; ++k) {
    int sj = srcs[k];
    float w = expf(lrelu(a_s[sj] + adi) - m) * inv;
    const unsigned short* xr = xcol + (size_t)sj * XBS;
    #pragma unroll
    for (int q = 0; q < 5; ++q) {
      ushort4 xv = *reinterpret_cast<const ushort4*>(xr + 4 * q);
      acc[4*q+0] += w * bf2f(xv.x);
      acc[4*q+1] += w * bf2f(xv.y);
      acc[4*q+2] += w * bf2f(xv.z);
      acc[4*q+3] += w * bf2f(xv.w);
    }
  }
  float* op = out + (size_t)node * OUT_DIM + 20u * cc;
  const float* bp = bias + 20u * cc;
  #pragma unroll
  for (int q = 0; q < 5; ++q) {
    float4 b = *reinterpret_cast<const float4*>(bp + 4 * q);
    float4 o = {acc[4*q] + b.x, acc[4*q+1] + b.y, acc[4*q+2] + b.z, acc[4*q+3] + b.w};
    *reinterpret_cast<float4*>(op + 4 * q) = o;
  }
}

extern "C" void kernel_launch(void* const* d_in, const int* in_sizes, int n_in,
                              void* d_out, int out_size, void* d_ws, size_t ws_size,
                              hipStream_t stream) {
  const float* z     = (const float*)d_in[0];
  const int*   ei    = (const int*)d_in[1];     // int64 in ref -> int32 on the wire
  const float* W     = (const float*)d_in[2];
  const float* att_s = (const float*)d_in[3];
  const float* att_d = (const float*)d_in[4];
  const float* bias  = (const float*)d_in[5];
  float* out = (float*)d_out;

  char* ws = (char*)d_ws;
  size_t off = 0;
  unsigned short* xb = (unsigned short*)(ws + off); off += (size_t)N_NODES * XBS * 2;  // 30.4 MB
  unsigned short* Wb = (unsigned short*)(ws + off); off += (size_t)BNP * KP * 2;
  float*  a_s  = (float*)(ws + off);  off += 50048 * 4;
  float*  a_d  = (float*)(ws + off);  off += 50048 * 4;
  int*    deg  = (int*)(ws + off);    off += 50048 * 4;
  int*    offs = (int*)(ws + off);    off += 50056 * 4;
  int*    cur  = (int*)(ws + off);    off += 50048 * 4;
  int*    bsum = (int*)(ws + off);    off += 64 * 4;
  int*    bex  = (int*)(ws + off);    off += 64 * 4;
  int*    srcs = (int*)(ws + off);    off += (size_t)N_EDGES * 4;
  float2* minv = (float2*)(ws + off); off += (size_t)50048 * 8;

  (void)hipMemsetAsync(deg, 0, N_NODES * 4, stream);

  wconv<<<(BNP * KP / 8 + 255) / 256, 256, 0, stream>>>(W, Wb);
  gemm_x<<<GRID_M, 256, 0, stream>>>(z, Wb, att_s, att_d, xb, a_s, a_d);
  hist<<<(N_EDGES + 255) / 256, 256, 0, stream>>>(ei, deg);
  scan1<<<NBLK, SCAN_B, 0, stream>>>(deg, bsum);
  scan2<<<1, 64, 0, stream>>>(bsum, bex, offs);
  scan3<<<NBLK, SCAN_B, 0, stream>>>(deg, bex, offs, cur);
  fill<<<(N_EDGES + 255) / 256, 256, 0, stream>>>(ei, cur, srcs);
  minv_k<<<(N_NODES + 3) / 4, 256, 0, stream>>>(a_s, a_d, offs, srcs, minv);
  aggregate<<<((unsigned)N_NODES * CCH + 255) / 256, 256, 0, stream>>>(
      xb, a_s, a_d, minv, offs, srcs, bias, out);
}

// Round 9
// 329.422 us; speedup vs baseline: 1.2963x; 1.0110x over previous
//
#include <hip/hip_runtime.h>

#define N_NODES 50000
#define N_EDGES 800000
#define IN_DIM  1200
#define KP      1216               // Wb padded K
#define OUT_DIM 300
#define BNP     320                // Wb padded rows
#define XBS     304                // xb row stride (bf16)
#define BM      64
#define NKT     38                 // K-steps of 32 (covers 1216; tail guarded/zero)
#define GRID_M  ((N_NODES + BM - 1) / BM)   // 782

typedef __attribute__((ext_vector_type(8))) short short8;
typedef __attribute__((ext_vector_type(4))) float f32x4;

__device__ __forceinline__ short f2bf(float f) {
  unsigned u = __builtin_bit_cast(unsigned, f);
  u += 0x7fffu + ((u >> 16) & 1u);            // RNE
  return (short)(u >> 16);
}
__device__ __forceinline__ float bf2f(unsigned short h) {
  return __builtin_bit_cast(float, (unsigned)h << 16);
}
__device__ __forceinline__ float lrelu(float v) { return v > 0.f ? v : 0.2f * v; }

__device__ __forceinline__ float wredMaxF(float v) {
  #pragma unroll
  for (int o = 32; o > 0; o >>= 1) v = fmaxf(v, __shfl_xor(v, o));
  return v;
}
__device__ __forceinline__ float wredSumF(float v) {
  #pragma unroll
  for (int o = 32; o > 0; o >>= 1) v += __shfl_xor(v, o);
  return v;
}

// async 16B/lane global->LDS DMA; lds dest must be wave-uniform (HW adds lane*16)
__device__ __forceinline__ void gl_lds16(const unsigned short* g, unsigned short* l) {
  __builtin_amdgcn_global_load_lds(
      (const __attribute__((address_space(1))) unsigned int*)g,
      (__attribute__((address_space(3))) unsigned int*)l, 16, 0, 0);
}

// ---------------- W -> bf16, padded [320][1216]
__global__ __launch_bounds__(256) void wconv(const float* __restrict__ W,
                                             unsigned short* __restrict__ Wb) {
  int f = blockIdx.x * 256 + threadIdx.x;
  if (f >= BNP * KP / 8) return;
  int n = (f * 8) / KP, c = (f * 8) % KP;
  short8 v = {0,0,0,0,0,0,0,0};
  if (n < OUT_DIM && c < IN_DIM) {
    const float4* p = reinterpret_cast<const float4*>(W + (size_t)n * IN_DIM + c);
    float4 f0 = p[0], f1 = p[1];
    v[0]=f2bf(f0.x); v[1]=f2bf(f0.y); v[2]=f2bf(f0.z); v[3]=f2bf(f0.w);
    v[4]=f2bf(f1.x); v[5]=f2bf(f1.y); v[6]=f2bf(f1.z); v[7]=f2bf(f1.w);
  }
  *reinterpret_cast<short8*>(&Wb[(size_t)n * KP + c]) = v;
}

// ---------------- GEMM: xb = z @ W^T. BM=64, BN=320, BK=32, 4 waves (2Mw x 2Nw).
// B staged via global_load_lds DMA (async, no VGPR/VALU); A reg-staged f32->bf16
// (tiny, guards handle M/K tails). 64B LDS rows => conflict-free ds_read_b128.
__global__ __launch_bounds__(256) void gemm_x(const float* __restrict__ z,
                                              const unsigned short* __restrict__ Wb,
                                              const float* __restrict__ att_s,
                                              const float* __restrict__ att_d,
                                              unsigned short* __restrict__ xb,
                                              float* __restrict__ a_s,
                                              float* __restrict__ a_d) {
  __shared__ __align__(16) unsigned short As[2][BM * 32];    // 2 x 4 KB
  __shared__ __align__(16) unsigned short Bs[2][BNP * 32];   // 2 x 20 KB

  const int tid  = threadIdx.x;
  const int lane = tid & 63;
  const int wid  = tid >> 6;
  const int lr   = lane & 15;
  const int lg   = lane >> 4;
  const int mw   = wid >> 1;           // 0..1
  const int nw   = wid & 1;            // 0..1
  const int m0   = blockIdx.x * BM;

  f32x4 zero4 = {0.f, 0.f, 0.f, 0.f};
  const float4 fz4 = make_float4(0.f, 0.f, 0.f, 0.f);
  f32x4 acc[2][10];
  #pragma unroll
  for (int mf = 0; mf < 2; ++mf)
    #pragma unroll
    for (int nj = 0; nj < 10; ++nj) acc[mf][nj] = zero4;

  // A stage: thread -> row ra (0..63), k-chunk ka8 (8 f32)
  const int ra = tid >> 2, ka8 = (tid & 3) * 8;
  const int am = m0 + ra;
  float4 ga0, ga1;

  // B stage (DMA): per wave, issue j covers rows j*64 + wid*16 + lane/4
  const int brow = wid * 16 + (lane >> 2);
  const int bk8  = (lane & 3) * 8;

  #define LOADA(KT)                                                           \
    {                                                                         \
      int k = (KT) * 32 + ka8;                                                \
      if (am < N_NODES && k + 8 <= IN_DIM) {                                  \
        const float4* p = reinterpret_cast<const float4*>(z + (size_t)am * IN_DIM + k); \
        ga0 = p[0]; ga1 = p[1];                                               \
      } else { ga0 = fz4; ga1 = fz4; }                                        \
    }

  #define WRITEA(BUF)                                                         \
    {                                                                         \
      short8 v;                                                               \
      v[0]=f2bf(ga0.x); v[1]=f2bf(ga0.y); v[2]=f2bf(ga0.z); v[3]=f2bf(ga0.w); \
      v[4]=f2bf(ga1.x); v[5]=f2bf(ga1.y); v[6]=f2bf(ga1.z); v[7]=f2bf(ga1.w); \
      *reinterpret_cast<short8*>(&As[BUF][ra * 32 + ka8]) = v;                \
    }

  #define STAGEB(BUF, KT)                                                     \
    _Pragma("unroll")                                                         \
    for (int j = 0; j < 5; ++j) {                                             \
      const unsigned short* gsrc =                                            \
          Wb + (size_t)(j * 64 + brow) * KP + (KT) * 32 + bk8;                \
      unsigned short* ldst = &Bs[BUF][(j * 64 + wid * 16) * 32];              \
      gl_lds16(gsrc, ldst);                                                   \
    }

  // prologue: fill buffer 0
  STAGEB(0, 0);
  LOADA(0);
  WRITEA(0);
  __syncthreads();

  #pragma unroll 1
  for (int kt = 0; kt < NKT; ++kt) {
    const int cur = kt & 1;
    if (kt < NKT - 1) {
      STAGEB(cur ^ 1, kt + 1);       // async DMA, in flight across compute
      LOADA(kt + 1);
    }

    // A frags: row = mw*32 + mf*16 + lr, 16B each (conflict-free: 64B rows)
    short8 a0 = *reinterpret_cast<const short8*>(&As[cur][(mw * 32 + lr) * 32 + lg * 8]);
    short8 a1 = *reinterpret_cast<const short8*>(&As[cur][(mw * 32 + 16 + lr) * 32 + lg * 8]);
    // B frags: row = nw*160 + nj*16 + lr
    #pragma unroll
    for (int nj = 0; nj < 10; ++nj) {
      short8 b = *reinterpret_cast<const short8*>(
          &Bs[cur][(nw * 160 + nj * 16 + lr) * 32 + lg * 8]);
      acc[0][nj] = __builtin_amdgcn_mfma_f32_16x16x32_bf16(a0, b, acc[0][nj], 0, 0, 0);
      acc[1][nj] = __builtin_amdgcn_mfma_f32_16x16x32_bf16(a1, b, acc[1][nj], 0, 0, 0);
    }

    if (kt < NKT - 1) { WRITEA(cur ^ 1); }
    __syncthreads();                 // drains DMA + A write, releases cur
  }
  #undef LOADA
  #undef WRITEA
  #undef STAGEB

  // ---- epilogue: bf16 x store + fused logits, cross-nw LDS reduce
  float* red = reinterpret_cast<float*>(&As[0][0]);  // [2 sd][2 nw][64 rows] = 1 KB

  float ps[2][4] = {{0,0,0,0},{0,0,0,0}}, pd[2][4] = {{0,0,0,0},{0,0,0,0}};
  #pragma unroll
  for (int nj = 0; nj < 10; ++nj) {
    int c = nw * 160 + nj * 16 + lr;
    bool cv = c < OUT_DIM;
    float vs = cv ? att_s[c] : 0.f;
    float vd = cv ? att_d[c] : 0.f;
    #pragma unroll
    for (int mf = 0; mf < 2; ++mf) {
      #pragma unroll
      for (int jj = 0; jj < 4; ++jj) {
        float val = acc[mf][nj][jj];
        int r = m0 + mw * 32 + mf * 16 + 4 * lg + jj;
        if (cv && r < N_NODES) xb[(size_t)r * XBS + c] = (unsigned short)f2bf(val);
        ps[mf][jj] += val * vs;
        pd[mf][jj] += val * vd;
      }
    }
  }
  #pragma unroll
  for (int mf = 0; mf < 2; ++mf)
    #pragma unroll
    for (int jj = 0; jj < 4; ++jj) {
      #pragma unroll
      for (int o = 8; o > 0; o >>= 1) {
        ps[mf][jj] += __shfl_xor(ps[mf][jj], o);
        pd[mf][jj] += __shfl_xor(pd[mf][jj], o);
      }
      if (lr == 0) {
        int rr = mw * 32 + mf * 16 + 4 * lg + jj;
        red[nw * 64 + rr]       = ps[mf][jj];
        red[128 + nw * 64 + rr] = pd[mf][jj];
      }
    }
  __syncthreads();
  if (tid < 64) {
    int r = m0 + tid;
    if (r < N_NODES) a_s[r] = red[tid] + red[64 + tid];
  } else if (tid < 128) {
    int t = tid - 64, r = m0 + t;
    if (r < N_NODES) a_d[r] = red[128 + t] + red[192 + t];
  }
}

// ---------------- CSR build (edges only; self-loops handled analytically)
__global__ void hist(const int* __restrict__ ei, int* __restrict__ deg) {
  int e = blockIdx.x * blockDim.x + threadIdx.x;
  if (e < N_EDGES) {
    unsigned dst = (unsigned)ei[N_EDGES + e];
    if (dst < N_NODES) atomicAdd(&deg[dst], 1);
  }
}

#define SCAN_B 1024
#define NBLK   49

__global__ __launch_bounds__(SCAN_B) void scan1(const int* __restrict__ deg,
                                                int* __restrict__ bsum) {
  int i = blockIdx.x * SCAN_B + threadIdx.x;
  int v = (i < N_NODES) ? deg[i] : 0;
  #pragma unroll
  for (int o = 32; o > 0; o >>= 1) v += __shfl_xor(v, o);
  __shared__ int wt[16];
  if ((threadIdx.x & 63) == 0) wt[threadIdx.x >> 6] = v;
  __syncthreads();
  if (threadIdx.x == 0) {
    int t = 0;
    #pragma unroll
    for (int w = 0; w < 16; ++w) t += wt[w];
    bsum[blockIdx.x] = t;
  }
}

__global__ void scan2(const int* __restrict__ bsum, int* __restrict__ bex,
                      int* __restrict__ offs) {
  int l = threadIdx.x;
  int v = (l < NBLK) ? bsum[l] : 0;
  int incl = v;
  #pragma unroll
  for (int off = 1; off < 64; off <<= 1) {
    int u = __shfl_up(incl, off);
    if (l >= off) incl += u;
  }
  if (l < NBLK) bex[l] = incl - v;
  if (l == NBLK - 1) offs[N_NODES] = incl;
}

__global__ __launch_bounds__(SCAN_B) void scan3(const int* __restrict__ deg,
                                                const int* __restrict__ bex,
                                                int* __restrict__ offs,
                                                int* __restrict__ cursor) {
  int tid = threadIdx.x;
  int i = blockIdx.x * SCAN_B + tid;
  int lane = tid & 63, wid = tid >> 6;
  int v = (i < N_NODES) ? deg[i] : 0;
  int incl = v;
  #pragma unroll
  for (int off = 1; off < 64; off <<= 1) {
    int u = __shfl_up(incl, off);
    if (lane >= off) incl += u;
  }
  __shared__ int wt[16];
  if (lane == 63) wt[wid] = incl;
  __syncthreads();
  if (tid < 16) {
    int t = wt[tid];
    int sc = t;
    #pragma unroll
    for (int off = 1; off < 16; off <<= 1) {
      int u = __shfl_up(sc, off);
      if (tid >= off) sc += u;
    }
    wt[tid] = sc - t;
  }
  __syncthreads();
  int excl = incl - v + wt[wid] + bex[blockIdx.x];
  if (i < N_NODES) { offs[i] = excl; cursor[i] = excl; }
}

__global__ void fill(const int* __restrict__ ei, int* __restrict__ cursor,
                     int* __restrict__ srcs) {
  int e = blockIdx.x * blockDim.x + threadIdx.x;
  if (e < N_EDGES) {
    unsigned dst = (unsigned)ei[N_EDGES + e];
    unsigned src = (unsigned)ei[e];
    if (dst < N_NODES && src < N_NODES) {
      int pos = atomicAdd(&cursor[dst], 1);
      srcs[pos] = (int)src;
    }
  }
}

// ---------------- per-node softmax stats (m, 1/s) — wave per node
__global__ __launch_bounds__(256) void minv_k(const float* __restrict__ a_s,
                                              const float* __restrict__ a_d,
                                              const int* __restrict__ offs,
                                              const int* __restrict__ srcs,
                                              float2* __restrict__ minv) {
  int node = blockIdx.x * 4 + (threadIdx.x >> 6);
  if (node >= N_NODES) return;
  int lane = threadIdx.x & 63;
  int beg = offs[node], end = offs[node + 1];
  float adi = a_d[node];
  float eself = lrelu(a_s[node] + adi);

  float m = eself;
  for (int k = beg + lane; k < end; k += 64)
    m = fmaxf(m, lrelu(a_s[srcs[k]] + adi));
  m = wredMaxF(m);

  float s = 0.f;
  for (int k = beg + lane; k < end; k += 64)
    s += expf(lrelu(a_s[srcs[k]] + adi) - m);
  s = wredSumF(s) + expf(eself - m);
  if (lane == 0) minv[node] = make_float2(m, 1.0f / s);
}

// ---------------- streaming weighted gather: thread = (node, 20-col chunk)
#define CCH 15
__global__ __launch_bounds__(256) void aggregate(const unsigned short* __restrict__ xb,
                                                 const float* __restrict__ a_s,
                                                 const float* __restrict__ a_d,
                                                 const float2* __restrict__ minv,
                                                 const int* __restrict__ offs,
                                                 const int* __restrict__ srcs,
                                                 const float* __restrict__ bias,
                                                 float* __restrict__ out) {
  unsigned wi = blockIdx.x * 256u + threadIdx.x;
  if (wi >= (unsigned)N_NODES * CCH) return;
  unsigned node = wi / CCH;
  unsigned cc = wi - node * CCH;           // cols 20cc..20cc+19

  int beg = offs[node], end = offs[node + 1];
  float2 mi = minv[node];
  const float m = mi.x, inv = mi.y;
  const float adi = a_d[node];
  const float wself = expf(lrelu(a_s[node] + adi) - m) * inv;

  const unsigned short* xcol = xb + 20u * cc;

  float acc[20];
  {
    const unsigned short* xr = xcol + (size_t)node * XBS;
    #pragma unroll
    for (int q = 0; q < 5; ++q) {
      ushort4 xv = *reinterpret_cast<const ushort4*>(xr + 4 * q);
      acc[4*q+0] = wself * bf2f(xv.x);
      acc[4*q+1] = wself * bf2f(xv.y);
      acc[4*q+2] = wself * bf2f(xv.z);
      acc[4*q+3] = wself * bf2f(xv.w);
    }
  }

  for (int k = beg; k < end; ++k) {
    int sj = srcs[k];
    float w = expf(lrelu(a_s[sj] + adi) - m) * inv;
    const unsigned short* xr = xcol + (size_t)sj * XBS;
    #pragma unroll
    for (int q = 0; q < 5; ++q) {
      ushort4 xv = *reinterpret_cast<const ushort4*>(xr + 4 * q);
      acc[4*q+0] += w * bf2f(xv.x);
      acc[4*q+1] += w * bf2f(xv.y);
      acc[4*q+2] += w * bf2f(xv.z);
      acc[4*q+3] += w * bf2f(xv.w);
    }
  }
  float* op = out + (size_t)node * OUT_DIM + 20u * cc;
  const float* bp = bias + 20u * cc;
  #pragma unroll
  for (int q = 0; q < 5; ++q) {
    float4 b = *reinterpret_cast<const float4*>(bp + 4 * q);
    float4 o = {acc[4*q] + b.x, acc[4*q+1] + b.y, acc[4*q+2] + b.z, acc[4*q+3] + b.w};
    *reinterpret_cast<float4*>(op + 4 * q) = o;
  }
}

extern "C" void kernel_launch(void* const* d_in, const int* in_sizes, int n_in,
                              void* d_out, int out_size, void* d_ws, size_t ws_size,
                              hipStream_t stream) {
  const float* z     = (const float*)d_in[0];
  const int*   ei    = (const int*)d_in[1];     // int64 in ref -> int32 on the wire
  const float* W     = (const float*)d_in[2];
  const float* att_s = (const float*)d_in[3];
  const float* att_d = (const float*)d_in[4];
  const float* bias  = (const float*)d_in[5];
  float* out = (float*)d_out;

  char* ws = (char*)d_ws;
  size_t off = 0;
  unsigned short* xb = (unsigned short*)(ws + off); off += (size_t)N_NODES * XBS * 2;  // 30.4 MB
  unsigned short* Wb = (unsigned short*)(ws + off); off += (size_t)BNP * KP * 2;
  float*  a_s  = (float*)(ws + off);  off += 50048 * 4;
  float*  a_d  = (float*)(ws + off);  off += 50048 * 4;
  int*    deg  = (int*)(ws + off);    off += 50048 * 4;
  int*    offs = (int*)(ws + off);    off += 50056 * 4;
  int*    cur  = (int*)(ws + off);    off += 50048 * 4;
  int*    bsum = (int*)(ws + off);    off += 64 * 4;
  int*    bex  = (int*)(ws + off);    off += 64 * 4;
  int*    srcs = (int*)(ws + off);    off += (size_t)N_EDGES * 4;
  float2* minv = (float2*)(ws + off); off += (size_t)50048 * 8;

  (void)hipMemsetAsync(deg, 0, N_NODES * 4, stream);

  wconv<<<(BNP * KP / 8 + 255) / 256, 256, 0, stream>>>(W, Wb);
  gemm_x<<<GRID_M, 256, 0, stream>>>(z, Wb, att_s, att_d, xb, a_s, a_d);
  hist<<<(N_EDGES + 255) / 256, 256, 0, stream>>>(ei, deg);
  scan1<<<NBLK, SCAN_B, 0, stream>>>(deg, bsum);
  scan2<<<1, 64, 0, stream>>>(bsum, bex, offs);
  scan3<<<NBLK, SCAN_B, 0, stream>>>(deg, bex, offs, cur);
  fill<<<(N_EDGES + 255) / 256, 256, 0, stream>>>(ei, cur, srcs);
  minv_k<<<(N_NODES + 3) / 4, 256, 0, stream>>>(a_s, a_d, offs, srcs, minv);
  aggregate<<<((unsigned)N_NODES * CCH + 255) / 256, 256, 0, stream>>>(
      xb, a_s, a_d, minv, offs, srcs, bias, out);
}

// Round 10
// 329.285 us; speedup vs baseline: 1.2969x; 1.0004x over previous
//
#include <hip/hip_runtime.h>

#define N_NODES 50000
#define N_EDGES 800000
#define IN_DIM  1200
#define KP      1216               // Wb padded K
#define OUT_DIM 300
#define BNP     320                // Wb padded rows
#define XBS     304                // xb row stride (bf16)
#define BM      64
#define NKT     38                 // K-steps of 32
#define GRID_M  ((N_NODES + BM - 1) / BM)   // 782

typedef __attribute__((ext_vector_type(8))) short short8;
typedef __attribute__((ext_vector_type(4))) float f32x4;

__device__ __forceinline__ short f2bf(float f) {
  unsigned u = __builtin_bit_cast(unsigned, f);
  u += 0x7fffu + ((u >> 16) & 1u);            // RNE
  return (short)(u >> 16);
}
__device__ __forceinline__ float bf2f(unsigned short h) {
  return __builtin_bit_cast(float, (unsigned)h << 16);
}
__device__ __forceinline__ float lrelu(float v) { return v > 0.f ? v : 0.2f * v; }

__device__ __forceinline__ float wredMaxF(float v) {
  #pragma unroll
  for (int o = 32; o > 0; o >>= 1) v = fmaxf(v, __shfl_xor(v, o));
  return v;
}
__device__ __forceinline__ float wredSumF(float v) {
  #pragma unroll
  for (int o = 32; o > 0; o >>= 1) v += __shfl_xor(v, o);
  return v;
}

// async 16B/lane global->LDS DMA; lds dest wave-uniform (HW adds lane*16)
__device__ __forceinline__ void gl_lds16(const unsigned short* g, unsigned short* l) {
  __builtin_amdgcn_global_load_lds(
      (const __attribute__((address_space(1))) unsigned int*)g,
      (__attribute__((address_space(3))) unsigned int*)l, 16, 0, 0);
}

// ---------------- W -> bf16, padded [320][1216]
__global__ __launch_bounds__(256) void wconv(const float* __restrict__ W,
                                             unsigned short* __restrict__ Wb) {
  int f = blockIdx.x * 256 + threadIdx.x;
  if (f >= BNP * KP / 8) return;
  int n = (f * 8) / KP, c = (f * 8) % KP;
  short8 v = {0,0,0,0,0,0,0,0};
  if (n < OUT_DIM && c < IN_DIM) {
    const float4* p = reinterpret_cast<const float4*>(W + (size_t)n * IN_DIM + c);
    float4 f0 = p[0], f1 = p[1];
    v[0]=f2bf(f0.x); v[1]=f2bf(f0.y); v[2]=f2bf(f0.z); v[3]=f2bf(f0.w);
    v[4]=f2bf(f1.x); v[5]=f2bf(f1.y); v[6]=f2bf(f1.z); v[7]=f2bf(f1.w);
  }
  *reinterpret_cast<short8*>(&Wb[(size_t)n * KP + c]) = v;
}

// ---------------- GEMM: xb = z @ W^T. BM=64, BN=320(full), BK=32, 4 waves.
// All waves share A (64 rows); wave w owns cols 80w..80w+79 (4M x 5N frags).
// LDS XOR-swizzle: phys_chunk = chunk ^ ((row>>1)&3) -> conflict-free b128
// reads AND writes (8 lanes -> 8 distinct 16B slots). B staged via
// global_load_lds with the inverse permutation applied to the GLOBAL source.
__global__ __launch_bounds__(256) void gemm_x(const float* __restrict__ z,
                                              const unsigned short* __restrict__ Wb,
                                              const float* __restrict__ att_s,
                                              const float* __restrict__ att_d,
                                              unsigned short* __restrict__ xb,
                                              float* __restrict__ a_s,
                                              float* __restrict__ a_d) {
  __shared__ __align__(16) unsigned short As[2][BM * 32];    // 2 x 4 KB
  __shared__ __align__(16) unsigned short Bs[2][BNP * 32];   // 2 x 20 KB

  const int tid  = threadIdx.x;
  const int lane = tid & 63;
  const int wid  = tid >> 6;           // 0..3, owns cols 80*wid..
  const int lr   = lane & 15;
  const int lg   = lane >> 4;
  const int lrs  = (lr >> 1) & 3;      // read-side swizzle term
  const int m0   = blockIdx.x * BM;

  f32x4 zero4 = {0.f, 0.f, 0.f, 0.f};
  const float4 fz4 = make_float4(0.f, 0.f, 0.f, 0.f);
  f32x4 acc[4][5];
  #pragma unroll
  for (int mf = 0; mf < 4; ++mf)
    #pragma unroll
    for (int nj = 0; nj < 5; ++nj) acc[mf][nj] = zero4;

  // A stage: thread -> row ra (0..63), logical chunk kaL, physical kaP
  const int ra  = tid >> 2;
  const int kaL = tid & 3;
  const int kaP = kaL ^ ((ra >> 1) & 3);
  const int am  = m0 + ra;
  float4 ga0, ga1;

  // B DMA: lane l -> LDS row rb = j*64 + wid*16 + (l>>2), phys chunk l&3.
  // Global source must supply chunk (l&3) ^ ((rb>>1)&3) = (l&3) ^ ((l>>3)&3).
  const int brow = wid * 16 + (lane >> 2);
  const int bgc  = (lane & 3) ^ ((lane >> 3) & 3);   // pre-swizzled global chunk

  #define LOADA(KT)                                                           \
    {                                                                         \
      int k = (KT) * 32 + kaL * 8;                                            \
      if (am < N_NODES && k + 8 <= IN_DIM) {                                  \
        const float4* p = reinterpret_cast<const float4*>(z + (size_t)am * IN_DIM + k); \
        ga0 = p[0]; ga1 = p[1];                                               \
      } else { ga0 = fz4; ga1 = fz4; }                                        \
    }

  #define WRITEA(BUF)                                                         \
    {                                                                         \
      short8 v;                                                               \
      v[0]=f2bf(ga0.x); v[1]=f2bf(ga0.y); v[2]=f2bf(ga0.z); v[3]=f2bf(ga0.w); \
      v[4]=f2bf(ga1.x); v[5]=f2bf(ga1.y); v[6]=f2bf(ga1.z); v[7]=f2bf(ga1.w); \
      *reinterpret_cast<short8*>(&As[BUF][ra * 32 + kaP * 8]) = v;            \
    }

  #define STAGEB(BUF, KT)                                                     \
    _Pragma("unroll")                                                         \
    for (int j = 0; j < 5; ++j) {                                             \
      const unsigned short* gsrc =                                            \
          Wb + (size_t)(j * 64 + brow) * KP + (KT) * 32 + bgc * 8;            \
      unsigned short* ldst = &Bs[BUF][(j * 64 + wid * 16) * 32];              \
      gl_lds16(gsrc, ldst);                                                   \
    }

  STAGEB(0, 0);
  LOADA(0);
  WRITEA(0);
  __syncthreads();

  #pragma unroll 1
  for (int kt = 0; kt < NKT; ++kt) {
    const int cur = kt & 1;
    if (kt < NKT - 1) {
      STAGEB(cur ^ 1, kt + 1);       // async DMA toward other buffer
      LOADA(kt + 1);
    }

    // A frags: row = mf*16 + lr; chunk lg swizzled by lrs
    short8 a[4];
    #pragma unroll
    for (int mf = 0; mf < 4; ++mf)
      a[mf] = *reinterpret_cast<const short8*>(
          &As[cur][(mf * 16 + lr) * 32 + (lg ^ lrs) * 8]);
    // B frags: row = wid*80 + nj*16 + lr
    #pragma unroll
    for (int nj = 0; nj < 5; ++nj) {
      short8 b = *reinterpret_cast<const short8*>(
          &Bs[cur][(wid * 80 + nj * 16 + lr) * 32 + (lg ^ lrs) * 8]);
      #pragma unroll
      for (int mf = 0; mf < 4; ++mf)
        acc[mf][nj] = __builtin_amdgcn_mfma_f32_16x16x32_bf16(a[mf], b, acc[mf][nj], 0, 0, 0);
    }

    if (kt < NKT - 1) { WRITEA(cur ^ 1); }
    __syncthreads();                 // drains DMA + A write, releases cur
  }
  #undef LOADA
  #undef WRITEA
  #undef STAGEB

  // ---- epilogue: bf16 x store + fused logits, cross-wave (4 col-waves) reduce
  float* red = reinterpret_cast<float*>(&As[0][0]);  // [2 sd][4 wid][64 rows] = 2 KB

  float ps[4][4], pd[4][4];
  #pragma unroll
  for (int mf = 0; mf < 4; ++mf)
    #pragma unroll
    for (int jj = 0; jj < 4; ++jj) { ps[mf][jj] = 0.f; pd[mf][jj] = 0.f; }

  #pragma unroll
  for (int nj = 0; nj < 5; ++nj) {
    int c = wid * 80 + nj * 16 + lr;
    bool cv = c < OUT_DIM;
    float vs = cv ? att_s[c] : 0.f;
    float vd = cv ? att_d[c] : 0.f;
    #pragma unroll
    for (int mf = 0; mf < 4; ++mf) {
      #pragma unroll
      for (int jj = 0; jj < 4; ++jj) {
        float val = acc[mf][nj][jj];
        int r = m0 + mf * 16 + 4 * lg + jj;
        if (cv && r < N_NODES) xb[(size_t)r * XBS + c] = (unsigned short)f2bf(val);
        ps[mf][jj] += val * vs;
        pd[mf][jj] += val * vd;
      }
    }
  }
  #pragma unroll
  for (int mf = 0; mf < 4; ++mf)
    #pragma unroll
    for (int jj = 0; jj < 4; ++jj) {
      #pragma unroll
      for (int o = 8; o > 0; o >>= 1) {
        ps[mf][jj] += __shfl_xor(ps[mf][jj], o);
        pd[mf][jj] += __shfl_xor(pd[mf][jj], o);
      }
      if (lr == 0) {
        int rr = mf * 16 + 4 * lg + jj;
        red[wid * 64 + rr]       = ps[mf][jj];
        red[256 + wid * 64 + rr] = pd[mf][jj];
      }
    }
  __syncthreads();
  if (tid < 64) {
    int r = m0 + tid;
    if (r < N_NODES)
      a_s[r] = red[tid] + red[64 + tid] + red[128 + tid] + red[192 + tid];
  } else if (tid < 128) {
    int t = tid - 64, r = m0 + t;
    if (r < N_NODES)
      a_d[r] = red[256 + t] + red[256 + 64 + t] + red[256 + 128 + t] + red[256 + 192 + t];
  }
}

// ---------------- CSR build (edges only; self-loops handled analytically)
__global__ void hist(const int* __restrict__ ei, int* __restrict__ deg) {
  int e = blockIdx.x * blockDim.x + threadIdx.x;
  if (e < N_EDGES) {
    unsigned dst = (unsigned)ei[N_EDGES + e];
    if (dst < N_NODES) atomicAdd(&deg[dst], 1);
  }
}

#define SCAN_B 1024
#define NBLK   49

__global__ __launch_bounds__(SCAN_B) void scan1(const int* __restrict__ deg,
                                                int* __restrict__ bsum) {
  int i = blockIdx.x * SCAN_B + threadIdx.x;
  int v = (i < N_NODES) ? deg[i] : 0;
  #pragma unroll
  for (int o = 32; o > 0; o >>= 1) v += __shfl_xor(v, o);
  __shared__ int wt[16];
  if ((threadIdx.x & 63) == 0) wt[threadIdx.x >> 6] = v;
  __syncthreads();
  if (threadIdx.x == 0) {
    int t = 0;
    #pragma unroll
    for (int w = 0; w < 16; ++w) t += wt[w];
    bsum[blockIdx.x] = t;
  }
}

__global__ void scan2(const int* __restrict__ bsum, int* __restrict__ bex,
                      int* __restrict__ offs) {
  int l = threadIdx.x;
  int v = (l < NBLK) ? bsum[l] : 0;
  int incl = v;
  #pragma unroll
  for (int off = 1; off < 64; off <<= 1) {
    int u = __shfl_up(incl, off);
    if (l >= off) incl += u;
  }
  if (l < NBLK) bex[l] = incl - v;
  if (l == NBLK - 1) offs[N_NODES] = incl;
}

__global__ __launch_bounds__(SCAN_B) void scan3(const int* __restrict__ deg,
                                                const int* __restrict__ bex,
                                                int* __restrict__ offs,
                                                int* __restrict__ cursor) {
  int tid = threadIdx.x;
  int i = blockIdx.x * SCAN_B + tid;
  int lane = tid & 63, wid = tid >> 6;
  int v = (i < N_NODES) ? deg[i] : 0;
  int incl = v;
  #pragma unroll
  for (int off = 1; off < 64; off <<= 1) {
    int u = __shfl_up(incl, off);
    if (lane >= off) incl += u;
  }
  __shared__ int wt[16];
  if (lane == 63) wt[wid] = incl;
  __syncthreads();
  if (tid < 16) {
    int t = wt[tid];
    int sc = t;
    #pragma unroll
    for (int off = 1; off < 16; off <<= 1) {
      int u = __shfl_up(sc, off);
      if (tid >= off) sc += u;
    }
    wt[tid] = sc - t;
  }
  __syncthreads();
  int excl = incl - v + wt[wid] + bex[blockIdx.x];
  if (i < N_NODES) { offs[i] = excl; cursor[i] = excl; }
}

__global__ void fill(const int* __restrict__ ei, int* __restrict__ cursor,
                     int* __restrict__ srcs) {
  int e = blockIdx.x * blockDim.x + threadIdx.x;
  if (e < N_EDGES) {
    unsigned dst = (unsigned)ei[N_EDGES + e];
    unsigned src = (unsigned)ei[e];
    if (dst < N_NODES && src < N_NODES) {
      int pos = atomicAdd(&cursor[dst], 1);
      srcs[pos] = (int)src;
    }
  }
}

// ---------------- per-node softmax stats (m, 1/s) — wave per node
__global__ __launch_bounds__(256) void minv_k(const float* __restrict__ a_s,
                                              const float* __restrict__ a_d,
                                              const int* __restrict__ offs,
                                              const int* __restrict__ srcs,
                                              float2* __restrict__ minv) {
  int node = blockIdx.x * 4 + (threadIdx.x >> 6);
  if (node >= N_NODES) return;
  int lane = threadIdx.x & 63;
  int beg = offs[node], end = offs[node + 1];
  float adi = a_d[node];
  float eself = lrelu(a_s[node] + adi);

  float m = eself;
  for (int k = beg + lane; k < end; k += 64)
    m = fmaxf(m, lrelu(a_s[srcs[k]] + adi));
  m = wredMaxF(m);

  float s = 0.f;
  for (int k = beg + lane; k < end; k += 64)
    s += expf(lrelu(a_s[srcs[k]] + adi) - m);
  s = wredSumF(s) + expf(eself - m);
  if (lane == 0) minv[node] = make_float2(m, 1.0f / s);
}

// ---------------- streaming weighted gather: thread = (node, 20-col chunk)
#define CCH 15
__global__ __launch_bounds__(256) void aggregate(const unsigned short* __restrict__ xb,
                                                 const float* __restrict__ a_s,
                                                 const float* __restrict__ a_d,
                                                 const float2* __restrict__ minv,
                                                 const int* __restrict__ offs,
                                                 const int* __restrict__ srcs,
                                                 const float* __restrict__ bias,
                                                 float* __restrict__ out) {
  unsigned wi = blockIdx.x * 256u + threadIdx.x;
  if (wi >= (unsigned)N_NODES * CCH) return;
  unsigned node = wi / CCH;
  unsigned cc = wi - node * CCH;           // cols 20cc..20cc+19

  int beg = offs[node], end = offs[node + 1];
  float2 mi = minv[node];
  const float m = mi.x, inv = mi.y;
  const float adi = a_d[node];
  const float wself = expf(lrelu(a_s[node] + adi) - m) * inv;

  const unsigned short* xcol = xb + 20u * cc;

  float acc[20];
  {
    const unsigned short* xr = xcol + (size_t)node * XBS;
    #pragma unroll
    for (int q = 0; q < 5; ++q) {
      ushort4 xv = *reinterpret_cast<const ushort4*>(xr + 4 * q);
      acc[4*q+0] = wself * bf2f(xv.x);
      acc[4*q+1] = wself * bf2f(xv.y);
      acc[4*q+2] = wself * bf2f(xv.z);
      acc[4*q+3] = wself * bf2f(xv.w);
    }
  }

  for (int k = beg; k < end; ++k) {
    int sj = srcs[k];
    float w = expf(lrelu(a_s[sj] + adi) - m) * inv;
    const unsigned short* xr = xcol + (size_t)sj * XBS;
    #pragma unroll
    for (int q = 0; q < 5; ++q) {
      ushort4 xv = *reinterpret_cast<const ushort4*>(xr + 4 * q);
      acc[4*q+0] += w * bf2f(xv.x);
      acc[4*q+1] += w * bf2f(xv.y);
      acc[4*q+2] += w * bf2f(xv.z);
      acc[4*q+3] += w * bf2f(xv.w);
    }
  }
  float* op = out + (size_t)node * OUT_DIM + 20u * cc;
  const float* bp = bias + 20u * cc;
  #pragma unroll
  for (int q = 0; q < 5; ++q) {
    float4 b = *reinterpret_cast<const float4*>(bp + 4 * q);
    float4 o = {acc[4*q] + b.x, acc[4*q+1] + b.y, acc[4*q+2] + b.z, acc[4*q+3] + b.w};
    *reinterpret_cast<float4*>(op + 4 * q) = o;
  }
}

extern "C" void kernel_launch(void* const* d_in, const int* in_sizes, int n_in,
                              void* d_out, int out_size, void* d_ws, size_t ws_size,
                              hipStream_t stream) {
  const float* z     = (const float*)d_in[0];
  const int*   ei    = (const int*)d_in[1];     // int64 in ref -> int32 on the wire
  const float* W     = (const float*)d_in[2];
  const float* att_s = (const float*)d_in[3];
  const float* att_d = (const float*)d_in[4];
  const float* bias  = (const float*)d_in[5];
  float* out = (float*)d_out;

  char* ws = (char*)d_ws;
  size_t off = 0;
  unsigned short* xb = (unsigned short*)(ws + off); off += (size_t)N_NODES * XBS * 2;  // 30.4 MB
  unsigned short* Wb = (unsigned short*)(ws + off); off += (size_t)BNP * KP * 2;
  float*  a_s  = (float*)(ws + off);  off += 50048 * 4;
  float*  a_d  = (float*)(ws + off);  off += 50048 * 4;
  int*    deg  = (int*)(ws + off);    off += 50048 * 4;
  int*    offs = (int*)(ws + off);    off += 50056 * 4;
  int*    cur  = (int*)(ws + off);    off += 50048 * 4;
  int*    bsum = (int*)(ws + off);    off += 64 * 4;
  int*    bex  = (int*)(ws + off);    off += 64 * 4;
  int*    srcs = (int*)(ws + off);    off += (size_t)N_EDGES * 4;
  float2* minv = (float2*)(ws + off); off += (size_t)50048 * 8;

  (void)hipMemsetAsync(deg, 0, N_NODES * 4, stream);

  wconv<<<(BNP * KP / 8 + 255) / 256, 256, 0, stream>>>(W, Wb);
  gemm_x<<<GRID_M, 256, 0, stream>>>(z, Wb, att_s, att_d, xb, a_s, a_d);
  hist<<<(N_EDGES + 255) / 256, 256, 0, stream>>>(ei, deg);
  scan1<<<NBLK, SCAN_B, 0, stream>>>(deg, bsum);
  scan2<<<1, 64, 0, stream>>>(bsum, bex, offs);
  scan3<<<NBLK, SCAN_B, 0, stream>>>(deg, bex, offs, cur);
  fill<<<(N_EDGES + 255) / 256, 256, 0, stream>>>(ei, cur, srcs);
  minv_k<<<(N_NODES + 3) / 4, 256, 0, stream>>>(a_s, a_d, offs, srcs, minv);
  aggregate<<<((unsigned)N_NODES * CCH + 255) / 256, 256, 0, stream>>>(
      xb, a_s, a_d, minv, offs, srcs, bias, out);
}